// Round 5
// baseline (24.759 us; speedup 1.0000x reference)
//
#include <hip/hip_runtime.h>

// out[o] = sum_t d1[t + o - 301] * d2[t],  o in [0,603), t in [0,3000)
// Parity-split GEMM per channel:
//   o = 2*(16a + m) + par,  C_par[m,a] = sum_s d1[s + 2m + par - 301] * d2[s - 32a]
// mfma_f32_16x16x32_bf16; C/D: lane l reg rr -> row m=4*(l>>4)+rr, col n=l&15.
//
// Round 5: occupancy attack. Block = 2 channels x 2 K-halves = 4 waves
// (BLOCK=256), grid=1024 -> 4 blocks/CU = 4 waves/SIMD (VGPR<=128 via
// __launch_bounds__(256,4); B-FIFO dropped - it was perf-neutral in R3 and
// costs 64 VGPRs). Upfront cooperative staging (R2-proven), 48 k-steps per
// wave, K-halves summed through LDS scratch (stride 17) with two barriers.

#define NT    3000
#define NOUT  603
#define CHPB  2
#define BLOCK 256

// Per-channel LDS (bytes):
//   l1: 6784 B (1696 dw), ld1[e]=d1[e-304]; data dw [152,1652), pads zeroed.
//   l2: 8192 B (2048 dw), ld2[e]=d2[e-768]; data dw [384,1884), pads zeroed.
#define L1B  6784
#define L2B  8192
#define CHB  (L1B + L2B)      // 14976
#define TOTB (CHB * CHPB)     // 29952

typedef short bf16x8 __attribute__((ext_vector_type(8)));
typedef float f32x4  __attribute__((ext_vector_type(4)));

static __device__ __forceinline__ uint f2bf(float f) {
    union { float f; uint u; } a; a.f = f;            // RNE f32 -> bf16
    return (a.u + 0x7fffu + ((a.u >> 16) & 1u)) >> 16;
}

__global__ __launch_bounds__(BLOCK, 4) void xcorr_mfma(
    const float* __restrict__ d1g, const float* __restrict__ d2g,
    float* __restrict__ out)
{
    __shared__ __align__(16) unsigned char smem[TOTB];
    const int tid = threadIdx.x;
    const int chBase = blockIdx.x * CHPB;

    // --- Zero pad regions only.
    for (int i = tid; i < CHPB * 196; i += BLOCK) {
        const int c = i / 196, j = i % 196;
        const int dw = (j < 152) ? j : (1652 + (j - 152));
        ((uint*)(smem + c * CHB))[dw] = 0u;
    }
    for (int i = tid; i < CHPB * 548; i += BLOCK) {
        const int c = i / 548, j = i % 548;
        const int dw = (j < 384) ? j : (1884 + (j - 384));
        ((uint*)(smem + c * CHB + L1B))[dw] = 0u;
    }

    // --- Stage d1 -> bf16 at element 304 (byte 608); d2 at element 768.
    for (int i = tid; i < CHPB * 750; i += BLOCK) {
        const int c = i / 750, j = i % 750;
        const float4 v = *(const float4*)(d1g + (size_t)(chBase + c) * NT + 4 * j);
        uint2 p;
        p.x = f2bf(v.x) | (f2bf(v.y) << 16);
        p.y = f2bf(v.z) | (f2bf(v.w) << 16);
        *(uint2*)(smem + c * CHB + 608 + 8 * j) = p;
    }
    for (int i = tid; i < CHPB * 750; i += BLOCK) {
        const int c = i / 750, j = i % 750;
        const float4 v = *(const float4*)(d2g + (size_t)(chBase + c) * NT + 4 * j);
        uint2 p;
        p.x = f2bf(v.x) | (f2bf(v.y) << 16);
        p.y = f2bf(v.z) | (f2bf(v.w) << 16);
        *(uint2*)(smem + c * CHB + L1B + 1536 + 8 * j) = p;
    }
    __syncthreads();

    // --- Wave (c, h): channel c, K-half h (k-steps [48h, 48h+48)).
    const int wid = tid >> 6, lane = tid & 63;
    const int c = wid >> 1, h = wid & 1;
    const int q = lane >> 4, r = lane & 15;
    const uint* lA = (const uint*)(smem + c * CHB);
    const uint* lB = (const uint*)(smem + c * CHB + L1B);

    f32x4 a00 = {0.f,0.f,0.f,0.f};   // aPT: P = parity, T = n-tile
    f32x4 a10 = {0.f,0.f,0.f,0.f};
    f32x4 a01 = {0.f,0.f,0.f,0.f};
    f32x4 a11 = {0.f,0.f,0.f,0.f};

    int da = 130 + 4 * q + r + 768 * h;        // A dword base (+16/step)
    int db = 512 + 4 * q - 16 * r + 768 * h;   // tile0 B dword base (+16/step)

    #pragma unroll 4
    for (int i = 0; i < 48; ++i) {
        const uint* pa = lA + da;
        const uint Dm1 = pa[-1], D0 = pa[0], D1 = pa[1], D2 = pa[2], D3 = pa[3];

        union { uint w[4]; bf16x8 v; int4 i4; } f1, f0, g0, g1u;
        f1.w[0] = D0; f1.w[1] = D1; f1.w[2] = D2; f1.w[3] = D3;   // par=1
        f0.w[0] = (Dm1 >> 16) | (D0 << 16);                       // par=0
        f0.w[1] = (D0  >> 16) | (D1 << 16);
        f0.w[2] = (D1  >> 16) | (D2 << 16);
        f0.w[3] = (D2  >> 16) | (D3 << 16);

        g0.i4  = *(const int4*)(lB + db);        // n-tile a in [0,16)
        g1u.i4 = *(const int4*)(lB + db - 256);  // n-tile a in [16,32)

        a00 = __builtin_amdgcn_mfma_f32_16x16x32_bf16(f0.v, g0.v,  a00, 0, 0, 0);
        a10 = __builtin_amdgcn_mfma_f32_16x16x32_bf16(f1.v, g0.v,  a10, 0, 0, 0);
        a01 = __builtin_amdgcn_mfma_f32_16x16x32_bf16(f0.v, g1u.v, a01, 0, 0, 0);
        a11 = __builtin_amdgcn_mfma_f32_16x16x32_bf16(f1.v, g1u.v, a11, 0, 0, 0);

        da += 16; db += 16;
    }

    // --- Combine K-halves through LDS scratch (reuses l1 region; safe after
    // barrier: all A-reads are done). Stride 17 dwords -> conflict-free.
    __syncthreads();
    uint* S = (uint*)(smem + c * CHB);
    const int soff = lane * 17;
    if (h == 1) {
        *(f32x4*)(S + soff)      = a00;
        *(f32x4*)(S + soff + 4)  = a10;
        *(f32x4*)(S + soff + 8)  = a01;
        *(f32x4*)(S + soff + 12) = a11;
    }
    __syncthreads();
    if (h == 1) return;

    {
        const f32x4 b00 = *(const f32x4*)(S + soff);
        const f32x4 b10 = *(const f32x4*)(S + soff + 4);
        const f32x4 b01 = *(const f32x4*)(S + soff + 8);
        const f32x4 b11 = *(const f32x4*)(S + soff + 12);
        a00 += b00; a10 += b10; a01 += b01; a11 += b11;
    }

    // --- Store: lane (q,r), reg rr, parity p -> o = 512*tile + 32r + 8q + 2rr + p.
    float* o = out + (size_t)(chBase + c) * NOUT;
    {
        const int X = 32 * r + 8 * q;            // tile0: X+7 <= 511 < 603
        float4 s0 = {a00[0], a10[0], a00[1], a10[1]};
        float4 s1 = {a00[2], a10[2], a00[3], a10[3]};
        *(float4*)(o + X)     = s0;
        *(float4*)(o + X + 4) = s1;
    }
    {
        const int X = 512 + 32 * r + 8 * q;
        if (X + 7 < NOUT) {
            float4 s0 = {a01[0], a11[0], a01[1], a11[1]};
            float4 s1 = {a01[2], a11[2], a01[3], a11[3]};
            *(float4*)(o + X)     = s0;
            *(float4*)(o + X + 4) = s1;
        } else if (X < NOUT) {
            const float v[8] = {a01[0], a11[0], a01[1], a11[1],
                                a01[2], a11[2], a01[3], a11[3]};
            #pragma unroll
            for (int e = 0; e < 8; ++e)
                if (X + e < NOUT) o[X + e] = v[e];
        }
    }
}

extern "C" void kernel_launch(void* const* d_in, const int* in_sizes, int n_in,
                              void* d_out, int out_size, void* d_ws, size_t ws_size,
                              hipStream_t stream) {
    const float* d1 = (const float*)d_in[0];
    const float* d2 = (const float*)d_in[1];
    float* out = (float*)d_out;
    const int nChannels = in_sizes[0] / NT;     // 2048
    const int grid = nChannels / CHPB;          // 1024
    xcorr_mfma<<<grid, BLOCK, 0, stream>>>(d1, d2, out);
}

// Round 6
// 23.953 us; speedup vs baseline: 1.0337x; 1.0337x over previous
//
#include <hip/hip_runtime.h>

// out[o] = sum_t d1[t + o - 301] * d2[t],  o in [0,603), t in [0,3000)
// Parity-split GEMM per channel:
//   o = 2*(16a + m) + par,  C_par[m,a] = sum_s d1[s + 2m + par - 301] * d2[s - 32a]
// mfma_f32_16x16x32_bf16; C/D: lane l reg rr -> row m=4*(l>>4)+rr, col n=l&15.
//
// Round 6: streaming (R4) x K-split occupancy. Block = 1 channel x 2 K-half
// waves (BLOCK=128, grid=2048 -> 4 waves/SIMD). Each wave owns a PRIVATE LDS
// region covering its half's touch-range and streams its own staging through
// its 48 k-steps (issue loads early / convert+ds_write late). No cross-wave
// sync until one final barrier to sum accumulators.
//
// Wave h (h=0,1), global k-steps I = i + 48h, i in [0,48):
//   global A dwords touched: [129+768h, 913+768h)  -> private pA origin A0=128+768h
//   global B dwords touched: [16+768h, 1280+768h)  -> private pB origin B0=16+768h
//   local da = 2+4q+r+16i (reads da-1..da+3), local db = 496+4q-16r+16i
//   (identical constants for both waves; algebraically == R3-verified globals)

#define NT    3000
#define NOUT  603
#define BLOCK 128
#define PA_SZ 788          // private A dwords (touch [1,785))
#define PB_SZ 1264         // private B dwords (touch [0,1264))
#define PW_SZ (PA_SZ + PB_SZ)   // 2052 dwords per wave

typedef short bf16x8 __attribute__((ext_vector_type(8)));
typedef float f32x4  __attribute__((ext_vector_type(4)));

static __device__ __forceinline__ uint f2bf(float f) {
    union { float f; uint u; } a; a.f = f;            // RNE f32 -> bf16
    return (a.u + 0x7fffu + ((a.u >> 16) & 1u)) >> 16;
}

static __device__ __forceinline__ int4 pack8(float4 v, float4 w) {
    int4 p;
    p.x = (int)(f2bf(v.x) | (f2bf(v.y) << 16));
    p.y = (int)(f2bf(v.z) | (f2bf(v.w) << 16));
    p.z = (int)(f2bf(w.x) | (f2bf(w.y) << 16));
    p.w = (int)(f2bf(w.z) | (f2bf(w.w) << 16));
    return p;
}

__global__ __launch_bounds__(BLOCK, 4) void xcorr_mfma(
    const float* __restrict__ d1g, const float* __restrict__ d2g,
    float* __restrict__ out)
{
    __shared__ __align__(16) uint smem[2 * PW_SZ];

    const int tid  = threadIdx.x;
    const int h    = tid >> 6;
    const int lane = tid & 63;
    const int q = lane >> 4, r = lane & 15;
    const int ch = blockIdx.x;
    const float* __restrict__ g1 = d1g + (size_t)ch * NT;
    const float* __restrict__ g2 = d2g + (size_t)ch * NT;

    uint* pA = smem + h * PW_SZ;
    uint* pB = pA + PA_SZ;
    const int A0 = 128 + 768 * h;   // global dword origin of pA
    const int B0 = 16  + 768 * h;   // global dword origin of pB

    // Immediate stage of one 16B unit at local dword d (d%4==0). All stage
    // units are fully-in-data or fully-pad (origins and data bounds are all
    // 0 mod 4 dwords), so a single per-unit guard suffices; pads write zeros.
    auto stageA = [&](int d) {
        const int e0 = 2 * (A0 + d - 152);            // d1 element index
        int4 p = {0, 0, 0, 0};
        if (0 <= e0 && e0 < NT)
            p = pack8(*(const float4*)(g1 + e0), *(const float4*)(g1 + e0 + 4));
        *(int4*)(pA + d) = p;
    };
    auto stageB = [&](int d) {
        const int e0 = 2 * (B0 + d - 384);            // d2 element index
        int4 p = {0, 0, 0, 0};
        if (0 <= e0 && e0 < NT)
            p = pack8(*(const float4*)(g2 + e0), *(const float4*)(g2 + e0 + 4));
        *(int4*)(pB + d) = p;
    };

    // --- Prologue: A local [0,512), B local [0,768). (Chunk0 compute touches
    // A [1,273) and B [0,752).)
    stageA(4 * lane);
    stageA(256 + 4 * lane);
    stageB(4 * lane);
    stageB(256 + 4 * lane);
    stageB(512 + 4 * lane);

    f32x4 a00 = {0.f,0.f,0.f,0.f};   // aPT: P = parity, T = n-tile
    f32x4 a10 = {0.f,0.f,0.f,0.f};
    f32x4 a01 = {0.f,0.f,0.f,0.f};
    f32x4 a11 = {0.f,0.f,0.f,0.f};

    int da = 2 + 4 * q + r;          // +16/step; reads da-1 .. da+3
    int db = 496 + 4 * q - 16 * r;   // +16/step; reads db..+3 and db-256..-253

    auto compute16 = [&]() {
        #pragma unroll
        for (int u = 0; u < 16; ++u) {
            const uint* pa = pA + da;
            const uint Dm1 = pa[-1], D0 = pa[0], D1 = pa[1], D2 = pa[2], D3 = pa[3];

            union { uint w[4]; bf16x8 v; int4 i4; } f1, f0, gg0, gg1;
            f1.w[0] = D0; f1.w[1] = D1; f1.w[2] = D2; f1.w[3] = D3;   // par=1
            f0.w[0] = (Dm1 >> 16) | (D0 << 16);                       // par=0
            f0.w[1] = (D0  >> 16) | (D1 << 16);
            f0.w[2] = (D1  >> 16) | (D2 << 16);
            f0.w[3] = (D2  >> 16) | (D3 << 16);

            gg0.i4 = *(const int4*)(pB + db);        // n-tile a in [0,16)
            gg1.i4 = *(const int4*)(pB + db - 256);  // n-tile a in [16,32)

            a00 = __builtin_amdgcn_mfma_f32_16x16x32_bf16(f0.v, gg0.v, a00, 0, 0, 0);
            a10 = __builtin_amdgcn_mfma_f32_16x16x32_bf16(f1.v, gg0.v, a10, 0, 0, 0);
            a01 = __builtin_amdgcn_mfma_f32_16x16x32_bf16(f0.v, gg1.v, a01, 0, 0, 0);
            a11 = __builtin_amdgcn_mfma_f32_16x16x32_bf16(f1.v, gg1.v, a11, 0, 0, 0);

            da += 16; db += 16;
        }
    };

    // --- Chunk 0: issue loads for A[512,768), A[768,788), B[768,1024).
    {
        const int dA2 = 512 + 4 * lane;
        const int dA3 = 768 + 4 * lane;
        const int dB3 = 768 + 4 * lane;
        const int eA2 = 2 * (A0 + dA2 - 152);
        const int eA3 = 2 * (A0 + dA3 - 152);
        const int eB3 = 2 * (B0 + dB3 - 384);
        const bool doA3 = dA3 < PA_SZ;                  // lane < 5
        const bool okA2 = (0 <= eA2) && (eA2 < NT);
        const bool okA3 = doA3 && (0 <= eA3) && (eA3 < NT);
        const bool okB3 = (0 <= eB3) && (eB3 < NT);
        float4 vA2a, vA2b, vA3a, vA3b, vB3a, vB3b;
        if (okA2) { vA2a = *(const float4*)(g1 + eA2); vA2b = *(const float4*)(g1 + eA2 + 4); }
        if (okA3) { vA3a = *(const float4*)(g1 + eA3); vA3b = *(const float4*)(g1 + eA3 + 4); }
        if (okB3) { vB3a = *(const float4*)(g2 + eB3); vB3b = *(const float4*)(g2 + eB3 + 4); }

        compute16();

        int4 p = {0,0,0,0};
        if (okA2) p = pack8(vA2a, vA2b);
        *(int4*)(pA + dA2) = p;
        if (doA3) {
            int4 p3 = {0,0,0,0};
            if (okA3) p3 = pack8(vA3a, vA3b);
            *(int4*)(pA + dA3) = p3;
        }
        int4 pb3 = {0,0,0,0};
        if (okB3) pb3 = pack8(vB3a, vB3b);
        *(int4*)(pB + dB3) = pb3;
    }

    // --- Chunk 1: issue loads for B[1024,1264).
    {
        const int dB4 = 1024 + 4 * lane;
        const int eB4 = 2 * (B0 + dB4 - 384);
        const bool doB4 = dB4 < PB_SZ;                  // lane < 60
        const bool okB4 = doB4 && (0 <= eB4) && (eB4 < NT);
        float4 vB4a, vB4b;
        if (okB4) { vB4a = *(const float4*)(g2 + eB4); vB4b = *(const float4*)(g2 + eB4 + 4); }

        compute16();

        if (doB4) {
            int4 p = {0,0,0,0};
            if (okB4) p = pack8(vB4a, vB4b);
            *(int4*)(pB + dB4) = p;
        }
    }

    // --- Chunk 2: pure compute.
    compute16();

    // --- Sum the two K-halves: wave1 -> LDS scratch (its own private region,
    // done being read), one barrier, wave0 adds and stores.
    uint* S = smem + PW_SZ;            // wave1's full region, stride 20 (16B ok)
    if (h == 1) {
        const int soff = lane * 20;
        *(f32x4*)(S + soff)      = a00;
        *(f32x4*)(S + soff + 4)  = a10;
        *(f32x4*)(S + soff + 8)  = a01;
        *(f32x4*)(S + soff + 12) = a11;
    }
    __syncthreads();
    if (h == 1) return;

    {
        const int soff = lane * 20;
        a00 += *(const f32x4*)(S + soff);
        a10 += *(const f32x4*)(S + soff + 4);
        a01 += *(const f32x4*)(S + soff + 8);
        a11 += *(const f32x4*)(S + soff + 12);
    }

    // --- Store: lane (q,r), reg rr, parity p -> o = 512*tile + 32r + 8q + 2rr + p.
    float* o = out + (size_t)ch * NOUT;
    {
        const int X = 32 * r + 8 * q;            // tile0: X+7 <= 511 < 603
        float4 s0 = {a00[0], a10[0], a00[1], a10[1]};
        float4 s1 = {a00[2], a10[2], a00[3], a10[3]};
        *(float4*)(o + X)     = s0;
        *(float4*)(o + X + 4) = s1;
    }
    {
        const int X = 512 + 32 * r + 8 * q;
        if (X + 7 < NOUT) {
            float4 s0 = {a01[0], a11[0], a01[1], a11[1]};
            float4 s1 = {a01[2], a11[2], a01[3], a11[3]};
            *(float4*)(o + X)     = s0;
            *(float4*)(o + X + 4) = s1;
        } else if (X < NOUT) {
            const float v[8] = {a01[0], a11[0], a01[1], a11[1],
                                a01[2], a11[2], a01[3], a11[3]};
            #pragma unroll
            for (int e = 0; e < 8; ++e)
                if (X + e < NOUT) o[X + e] = v[e];
        }
    }
}

extern "C" void kernel_launch(void* const* d_in, const int* in_sizes, int n_in,
                              void* d_out, int out_size, void* d_ws, size_t ws_size,
                              hipStream_t stream) {
    const float* d1 = (const float*)d_in[0];
    const float* d2 = (const float*)d_in[1];
    float* out = (float*)d_out;
    const int nChannels = in_sizes[0] / NT;     // 2048
    xcorr_mfma<<<nChannels, BLOCK, 0, stream>>>(d1, d2, out);
}